// Round 2
// baseline (347.787 us; speedup 1.0000x reference)
//
#include <hip/hip_runtime.h>

typedef unsigned long long u64;

#define NTOK 131072
#define DIMS 1024
#define NT   256
#define TPB  64   // tokens per block in dist kernels

// ---------------------------------------------------------------------------
// Kernel A: build ternary signatures as 2-plane bitmasks.
// Tile t, word w = c*4+j: bit L = plane-pred of sig[t][c*256 + L*4 + j]
// (matches the ballot order of the float4 loads in the mask kernel).
// sig[t] = 32 u64: words 0..15 pos plane, 16..31 neg plane.
// ---------------------------------------------------------------------------
__global__ void sig_kernel(const float* __restrict__ base,
                           const float* __restrict__ deltas,
                           u64* __restrict__ sig)
{
    const int t    = blockIdx.x;    // tile 0..255
    const int lane = threadIdx.x;   // 0..63
    #pragma unroll
    for (int c = 0; c < 4; ++c) {
        #pragma unroll
        for (int j = 0; j < 4; ++j) {
            const int d = c * 256 + lane * 4 + j;
            const float b  = base[d];
            const float dl = (t > 0) ? deltas[(size_t)(t - 1) * DIMS + d] : 0.0f;
            const bool use_d = (dl != 0.0f);
            const bool pos = use_d ? (dl > 0.0f) : (b > 0.0f);
            const bool neg = use_d ? (dl < 0.0f) : (b < 0.0f);
            const u64 bp = __ballot(pos);
            const u64 bn = __ballot(neg);
            if (lane == 0) {
                sig[(size_t)t * 32 + (c * 4 + j)]      = bp;
                sig[(size_t)t * 32 + 16 + (c * 4 + j)] = bn;
            }
        }
    }
}

// ---------------------------------------------------------------------------
// Kernel B: pack x into per-token 2-plane bitmasks in global scratch.
// masks[tok] = 32 u64 (pos 0..15, neg 16..31), 256 B/token, 33.5 MB total.
// Coalesced float4 reads + ballots; lane0 writes the 32 words (L2 merges).
// Memory-bound on the 537 MB x read.
// ---------------------------------------------------------------------------
__global__ __launch_bounds__(256)
void mask_kernel(const float* __restrict__ x, u64* __restrict__ masks)
{
    const int lane = threadIdx.x & 63;
    const int w    = threadIdx.x >> 6;
    const int tbase = blockIdx.x * 32 + w * 8;   // 8 tokens per wave

    for (int tk = 0; tk < 8; ++tk) {
        const int tok = tbase + tk;
        const float4* xr = (const float4*)(x + (size_t)tok * DIMS);
        u64 bp[16], bn[16];
        #pragma unroll
        for (int c = 0; c < 4; ++c) {
            const float4 v = xr[c * 64 + lane];
            bp[c * 4 + 0] = __ballot(v.x > 0.0f);  bn[c * 4 + 0] = __ballot(v.x < 0.0f);
            bp[c * 4 + 1] = __ballot(v.y > 0.0f);  bn[c * 4 + 1] = __ballot(v.y < 0.0f);
            bp[c * 4 + 2] = __ballot(v.z > 0.0f);  bn[c * 4 + 2] = __ballot(v.z < 0.0f);
            bp[c * 4 + 3] = __ballot(v.w > 0.0f);  bn[c * 4 + 3] = __ballot(v.w < 0.0f);
        }
        if (lane == 0) {
            ulonglong2* mr = (ulonglong2*)(masks + (size_t)tok * 32);
            #pragma unroll
            for (int i = 0; i < 8; ++i) {
                ulonglong2 t; t.x = bp[2 * i]; t.y = bp[2 * i + 1];
                mr[i] = t;
            }
            #pragma unroll
            for (int i = 0; i < 8; ++i) {
                ulonglong2 t; t.x = bn[2 * i]; t.y = bn[2 * i + 1];
                mr[8 + i] = t;
            }
        }
    }
}

// ---------------------------------------------------------------------------
// Kernel C: distances + argmin. Wave w: lane L owns tile w*64+L, signature
// held in 64 VGPRs. Token mask rows are wave-uniform -> scalar (s_load)
// stream; dist = popcnt(mask ^ sig) over both planes (pure VALU, no LDS
// streaming). dist = popcnt(px^ps)+popcnt(nx^ns) == popx+pops-2*cross.
// ---------------------------------------------------------------------------
__global__ __launch_bounds__(256)
void dist_kernel_s(const u64* __restrict__ sig,
                   const u64* __restrict__ masks,
                   float* __restrict__ idx_out,
                   float* __restrict__ dist_out)
{
    __shared__ int lkey[TPB][4];

    const int lane = threadIdx.x & 63;
    const int w    = threadIdx.x >> 6;
    const int tile = w * 64 + lane;
    const int tok0 = blockIdx.x * TPB;

    u64 sp[16], sn[16];
    {
        const u64* sgp = sig + (size_t)tile * 32;
        #pragma unroll
        for (int i = 0; i < 16; ++i) sp[i] = sgp[i];
        #pragma unroll
        for (int i = 0; i < 16; ++i) sn[i] = sgp[16 + i];
    }

    for (int tok = 0; tok < TPB; ++tok) {
        const u64* __restrict__ mrow = masks + (size_t)(tok0 + tok) * 32;  // uniform addr -> s_load
        int c0 = 0, c1 = 0, c2 = 0, c3 = 0;
        #pragma unroll
        for (int i = 0; i < 16; i += 4) {
            c0 += __popcll(mrow[i + 0] ^ sp[i + 0]);
            c1 += __popcll(mrow[i + 1] ^ sp[i + 1]);
            c2 += __popcll(mrow[i + 2] ^ sp[i + 2]);
            c3 += __popcll(mrow[i + 3] ^ sp[i + 3]);
            c0 += __popcll(mrow[16 + i + 0] ^ sn[i + 0]);
            c1 += __popcll(mrow[16 + i + 1] ^ sn[i + 1]);
            c2 += __popcll(mrow[16 + i + 2] ^ sn[i + 2]);
            c3 += __popcll(mrow[16 + i + 3] ^ sn[i + 3]);
        }
        const int dist = (c0 + c1) + (c2 + c3);
        dist_out[(size_t)(tok0 + tok) * NT + tile] = (float)dist;

        int key = (dist << 8) | tile;          // argmin, first-index tiebreak
        #pragma unroll
        for (int off = 32; off >= 1; off >>= 1)
            key = min(key, __shfl_xor(key, off));
        if (lane == 0) lkey[tok][w] = key;
    }
    __syncthreads();

    if (threadIdx.x < TPB) {
        const int tok = threadIdx.x;
        const int k = min(min(lkey[tok][0], lkey[tok][1]),
                          min(lkey[tok][2], lkey[tok][3]));
        idx_out[tok0 + tok] = (float)(k & 255);
    }
}

// ---------------------------------------------------------------------------
// Fallback (ws too small for masks): single fused kernel, LDS-staged masks.
// ---------------------------------------------------------------------------
__global__ __launch_bounds__(256)
void dist_kernel_lds(const float* __restrict__ x,
                     const u64* __restrict__ sig,
                     float* __restrict__ idx_out,
                     float* __restrict__ dist_out)
{
    __shared__ u64 lmask[TPB][32];
    __shared__ int lkey[TPB][4];

    const int lane = threadIdx.x & 63;
    const int w    = threadIdx.x >> 6;
    const int tile = w * 64 + lane;
    const int tok0 = blockIdx.x * TPB;

    u64 sp[16], sn[16];
    {
        const u64* sgp = sig + (size_t)tile * 32;
        #pragma unroll
        for (int i = 0; i < 16; ++i) sp[i] = sgp[i];
        #pragma unroll
        for (int i = 0; i < 16; ++i) sn[i] = sgp[16 + i];
    }

    for (int tk = 0; tk < 16; ++tk) {
        const int tok = w * 16 + tk;
        const float4* xr = (const float4*)(x + (size_t)(tok0 + tok) * DIMS);
        #pragma unroll
        for (int c = 0; c < 4; ++c) {
            const float4 v = xr[c * 64 + lane];
            const u64 bp0 = __ballot(v.x > 0.0f); const u64 bn0 = __ballot(v.x < 0.0f);
            const u64 bp1 = __ballot(v.y > 0.0f); const u64 bn1 = __ballot(v.y < 0.0f);
            const u64 bp2 = __ballot(v.z > 0.0f); const u64 bn2 = __ballot(v.z < 0.0f);
            const u64 bp3 = __ballot(v.w > 0.0f); const u64 bn3 = __ballot(v.w < 0.0f);
            if (lane == 0) {
                lmask[tok][c * 4 + 0] = bp0;  lmask[tok][16 + c * 4 + 0] = bn0;
                lmask[tok][c * 4 + 1] = bp1;  lmask[tok][16 + c * 4 + 1] = bn1;
                lmask[tok][c * 4 + 2] = bp2;  lmask[tok][16 + c * 4 + 2] = bn2;
                lmask[tok][c * 4 + 3] = bp3;  lmask[tok][16 + c * 4 + 3] = bn3;
            }
        }
    }
    __syncthreads();

    for (int tok = 0; tok < TPB; ++tok) {
        int c0 = 0, c1 = 0, c2 = 0, c3 = 0;
        #pragma unroll
        for (int i = 0; i < 16; i += 4) {
            c0 += __popcll(lmask[tok][i + 0] ^ sp[i + 0]);
            c1 += __popcll(lmask[tok][i + 1] ^ sp[i + 1]);
            c2 += __popcll(lmask[tok][i + 2] ^ sp[i + 2]);
            c3 += __popcll(lmask[tok][i + 3] ^ sp[i + 3]);
            c0 += __popcll(lmask[tok][16 + i + 0] ^ sn[i + 0]);
            c1 += __popcll(lmask[tok][16 + i + 1] ^ sn[i + 1]);
            c2 += __popcll(lmask[tok][16 + i + 2] ^ sn[i + 2]);
            c3 += __popcll(lmask[tok][16 + i + 3] ^ sn[i + 3]);
        }
        const int dist = (c0 + c1) + (c2 + c3);
        dist_out[(size_t)(tok0 + tok) * NT + tile] = (float)dist;

        int key = (dist << 8) | tile;
        #pragma unroll
        for (int off = 32; off >= 1; off >>= 1)
            key = min(key, __shfl_xor(key, off));
        if (lane == 0) lkey[tok][w] = key;
    }
    __syncthreads();

    if (threadIdx.x < TPB) {
        const int tok = threadIdx.x;
        const int k = min(min(lkey[tok][0], lkey[tok][1]),
                          min(lkey[tok][2], lkey[tok][3]));
        idx_out[tok0 + tok] = (float)(k & 255);
    }
}

extern "C" void kernel_launch(void* const* d_in, const int* in_sizes, int n_in,
                              void* d_out, int out_size, void* d_ws, size_t ws_size,
                              hipStream_t stream)
{
    const float* x      = (const float*)d_in[0];
    const float* base   = (const float*)d_in[1];
    const float* deltas = (const float*)d_in[2];

    u64* sig   = (u64*)d_ws;                         // 64 KB
    u64* masks = (u64*)((char*)d_ws + 65536);        // 33.5 MB

    float* idx_out  = (float*)d_out;                 // N floats (tile indices)
    float* dist_out = idx_out + NTOK;                // N*T floats

    const size_t need = 65536 + (size_t)NTOK * 32 * sizeof(u64);

    sig_kernel<<<NT, 64, 0, stream>>>(base, deltas, sig);
    if (ws_size >= need) {
        mask_kernel<<<NTOK / 32, 256, 0, stream>>>(x, masks);
        dist_kernel_s<<<NTOK / TPB, 256, 0, stream>>>(sig, masks, idx_out, dist_out);
    } else {
        dist_kernel_lds<<<NTOK / TPB, 256, 0, stream>>>(x, sig, idx_out, dist_out);
    }
}

// Round 6
// 304.887 us; speedup vs baseline: 1.1407x; 1.1407x over previous
//
#include <hip/hip_runtime.h>

typedef unsigned long long u64;
typedef unsigned int u32;

#define NTOK 131072
#define DIMS 1024
#define NT   256

// ---------------------------------------------------------------------------
// Kernel A: build ternary signatures as 2-plane bitmasks.
// Tile t, word k = c*4+j: bit L = plane-pred of sig[t][c*256 + L*4 + j]
// (matches the ballot order of the dist kernel's phase-1 float4 loads).
// sig[t] = 32 u64: words 0..15 pos plane, 16..31 neg plane.
// ---------------------------------------------------------------------------
__global__ void sig_kernel(const float* __restrict__ base,
                           const float* __restrict__ deltas,
                           u64* __restrict__ sig)
{
    const int t    = blockIdx.x;    // tile 0..255
    const int lane = threadIdx.x;   // 0..63
    #pragma unroll
    for (int c = 0; c < 4; ++c) {
        #pragma unroll
        for (int j = 0; j < 4; ++j) {
            const int d = c * 256 + lane * 4 + j;
            const float b  = base[d];
            const float dl = (t > 0) ? deltas[(size_t)(t - 1) * DIMS + d] : 0.0f;
            const bool use_d = (dl != 0.0f);
            const bool pos = use_d ? (dl > 0.0f) : (b > 0.0f);
            const bool neg = use_d ? (dl < 0.0f) : (b < 0.0f);
            const u64 bp = __ballot(pos);
            const u64 bn = __ballot(neg);
            if (lane == 0) {
                sig[(size_t)t * 32 + (c * 4 + j)]      = bp;
                sig[(size_t)t * 32 + 16 + (c * 4 + j)] = bn;
            }
        }
    }
}

// ---------------------------------------------------------------------------
// Kernel B (fused):
// Phase 1 (R1-verified): 4 waves x 16 tokens ballot-pack x signs into LDS
//   lmask[tok][word] (u64, row stride 33 to break bank alignment).
// Phase 2: one-time gather — lane L pulls token (tok0+L)'s 32 u64 masks
//   into 64 VGPRs. LDS is NOT touched in the hot loop.
// Phase 3: wave w scans tiles [64w, 64w+64). Signature rows are streamed
//   through SGPRs (readfirstlane-forced uniform address -> s_load); inner
//   loop is pure VALU xor+popcount; argmin = per-lane running min over
//   key=(dist<<8)|t. Cross-wave argmin combine via 1 KB LDS.
// ---------------------------------------------------------------------------
__global__ __launch_bounds__(256, 4)
void dist_kernel(const float* __restrict__ x,
                 const u64* __restrict__ sig,
                 float* __restrict__ idx_out,
                 float* __restrict__ dist_out)
{
    __shared__ u64 lmask[64][33];   // 16.9 KB, +1 u64 pad per row
    __shared__ int lkey[4][64];

    const int lane = threadIdx.x & 63;
    const int w    = threadIdx.x >> 6;
    const int tok0 = blockIdx.x * 64;

    // ---- phase 1: ballot-pack 64 token rows into LDS (wave w: 16 tokens) ----
    for (int tk = 0; tk < 16; ++tk) {
        const int tok = w * 16 + tk;
        const float4* xr = (const float4*)(x + (size_t)(tok0 + tok) * DIMS);
        #pragma unroll
        for (int c = 0; c < 4; ++c) {
            const float4 v = xr[c * 64 + lane];
            const u64 bp0 = __ballot(v.x > 0.0f); const u64 bn0 = __ballot(v.x < 0.0f);
            const u64 bp1 = __ballot(v.y > 0.0f); const u64 bn1 = __ballot(v.y < 0.0f);
            const u64 bp2 = __ballot(v.z > 0.0f); const u64 bn2 = __ballot(v.z < 0.0f);
            const u64 bp3 = __ballot(v.w > 0.0f); const u64 bn3 = __ballot(v.w < 0.0f);
            if (lane == 0) {
                lmask[tok][c * 4 + 0] = bp0;  lmask[tok][16 + c * 4 + 0] = bn0;
                lmask[tok][c * 4 + 1] = bp1;  lmask[tok][16 + c * 4 + 1] = bn1;
                lmask[tok][c * 4 + 2] = bp2;  lmask[tok][16 + c * 4 + 2] = bn2;
                lmask[tok][c * 4 + 3] = bp3;  lmask[tok][16 + c * 4 + 3] = bn3;
            }
        }
    }
    __syncthreads();

    // ---- phase 2: one-time gather of this lane's token masks into VGPRs ----
    u32 m[64];
    {
        const u64* mrow = &lmask[lane][0];
        #pragma unroll
        for (int k = 0; k < 32; ++k) {
            const u64 v = mrow[k];
            m[2 * k]     = (u32)v;
            m[2 * k + 1] = (u32)(v >> 32);
        }
    }

    // ---- phase 3: 64 tiles for this wave, SGPR-streamed signatures ----
    const int tbase = __builtin_amdgcn_readfirstlane(w * 64);  // provably uniform
    int bestkey = 0x7fffffff;
    float* drow = dist_out + (size_t)(tok0 + lane) * NT + tbase;
    for (int t4 = 0; t4 < 64; t4 += 4) {
        float darr[4];
        #pragma unroll
        for (int u = 0; u < 4; ++u) {
            const int t = tbase + t4 + u;
            const u32* __restrict__ srow = (const u32*)(sig + (size_t)t * 32);
            int a0 = 0, a1 = 0, a2 = 0, a3 = 0;
            #pragma unroll
            for (int k = 0; k < 64; k += 4) {
                a0 += __popc(m[k + 0] ^ srow[k + 0]);
                a1 += __popc(m[k + 1] ^ srow[k + 1]);
                a2 += __popc(m[k + 2] ^ srow[k + 2]);
                a3 += __popc(m[k + 3] ^ srow[k + 3]);
            }
            const int dist = (a0 + a1) + (a2 + a3);
            bestkey = min(bestkey, (dist << 8) | t);
            darr[u] = (float)dist;
        }
        float4 dv; dv.x = darr[0]; dv.y = darr[1]; dv.z = darr[2]; dv.w = darr[3];
        *(float4*)(drow + t4) = dv;   // 16B/lane, 1 KB stride; L2 merges lines
    }

    // ---- combine the 4 tile-quarters for argmin ----
    lkey[w][lane] = bestkey;
    __syncthreads();
    if (w == 0) {
        const int k = min(min(lkey[0][lane], lkey[1][lane]),
                          min(lkey[2][lane], lkey[3][lane]));
        idx_out[tok0 + lane] = (float)(k & 255);
    }
}

extern "C" void kernel_launch(void* const* d_in, const int* in_sizes, int n_in,
                              void* d_out, int out_size, void* d_ws, size_t ws_size,
                              hipStream_t stream)
{
    const float* x      = (const float*)d_in[0];
    const float* base   = (const float*)d_in[1];
    const float* deltas = (const float*)d_in[2];

    u64* sig = (u64*)d_ws;                           // 256*32*8 = 64 KB

    float* idx_out  = (float*)d_out;                 // N floats (tile indices)
    float* dist_out = idx_out + NTOK;                // N*T floats

    sig_kernel<<<NT, 64, 0, stream>>>(base, deltas, sig);
    dist_kernel<<<NTOK / 64, 256, 0, stream>>>(x, sig, idx_out, dist_out);
}

// Round 7
// 294.803 us; speedup vs baseline: 1.1797x; 1.0342x over previous
//
#include <hip/hip_runtime.h>

typedef unsigned long long u64;
typedef unsigned int u32;

#define NTOK 131072
#define DIMS 1024
#define NT   256

// ---------------------------------------------------------------------------
// Kernel A: build ternary signatures as 2-plane bitmasks.
// Tile t, word k = c*4+j: bit L = plane-pred of sig[t][c*256 + L*4 + j]
// (matches the ballot order of the dist kernel's phase-1 float4 loads).
// sig[t] = 32 u64: words 0..15 pos plane, 16..31 neg plane.
// ---------------------------------------------------------------------------
__global__ void sig_kernel(const float* __restrict__ base,
                           const float* __restrict__ deltas,
                           u64* __restrict__ sig)
{
    const int t    = blockIdx.x;    // tile 0..255
    const int lane = threadIdx.x;   // 0..63
    #pragma unroll
    for (int c = 0; c < 4; ++c) {
        #pragma unroll
        for (int j = 0; j < 4; ++j) {
            const int d = c * 256 + lane * 4 + j;
            const float b  = base[d];
            const float dl = (t > 0) ? deltas[(size_t)(t - 1) * DIMS + d] : 0.0f;
            const bool use_d = (dl != 0.0f);
            const bool pos = use_d ? (dl > 0.0f) : (b > 0.0f);
            const bool neg = use_d ? (dl < 0.0f) : (b < 0.0f);
            const u64 bp = __ballot(pos);
            const u64 bn = __ballot(neg);
            if (lane == 0) {
                sig[(size_t)t * 32 + (c * 4 + j)]      = bp;
                sig[(size_t)t * 32 + 16 + (c * 4 + j)] = bn;
            }
        }
    }
}

// ---------------------------------------------------------------------------
// Kernel B (fused):
// Phase 1: 4 waves x 16 tokens ballot-pack x signs into LDS lmask.
// Phase 2: one-time gather — lane L pulls token (tok0+L)'s masks into 64
//   VGPRs, then an opaque register asm pins them there (R6 lesson: without
//   it the compiler remats the loads inside the hot loop -> LDS-bound).
// Phase 3: wave w scans tiles [64w, 64w+64). Signatures stream through
//   SGPRs (uniform s_load); inner loop pure VALU xor+popcount; per-lane
//   running argmin. Distances buffered 32/lane and stored as 8 consecutive
//   float4 = one aligned 128B line per burst (R6 lesson: 16B stores spread
//   in time caused 3x HBM write amplification).
// ---------------------------------------------------------------------------
__global__ __launch_bounds__(256, 4)
void dist_kernel(const float* __restrict__ x,
                 const u64* __restrict__ sig,
                 float* __restrict__ idx_out,
                 float* __restrict__ dist_out)
{
    __shared__ u64 lmask[64][33];   // 16.9 KB, +1 u64 pad per row
    __shared__ int lkey[4][64];

    const int lane = threadIdx.x & 63;
    const int w    = threadIdx.x >> 6;
    const int tok0 = blockIdx.x * 64;

    // ---- phase 1: ballot-pack 64 token rows into LDS (wave w: 16 tokens) ----
    for (int tk = 0; tk < 16; ++tk) {
        const int tok = w * 16 + tk;
        const float4* xr = (const float4*)(x + (size_t)(tok0 + tok) * DIMS);
        #pragma unroll
        for (int c = 0; c < 4; ++c) {
            const float4 v = xr[c * 64 + lane];
            const u64 bp0 = __ballot(v.x > 0.0f); const u64 bn0 = __ballot(v.x < 0.0f);
            const u64 bp1 = __ballot(v.y > 0.0f); const u64 bn1 = __ballot(v.y < 0.0f);
            const u64 bp2 = __ballot(v.z > 0.0f); const u64 bn2 = __ballot(v.z < 0.0f);
            const u64 bp3 = __ballot(v.w > 0.0f); const u64 bn3 = __ballot(v.w < 0.0f);
            if (lane == 0) {
                lmask[tok][c * 4 + 0] = bp0;  lmask[tok][16 + c * 4 + 0] = bn0;
                lmask[tok][c * 4 + 1] = bp1;  lmask[tok][16 + c * 4 + 1] = bn1;
                lmask[tok][c * 4 + 2] = bp2;  lmask[tok][16 + c * 4 + 2] = bn2;
                lmask[tok][c * 4 + 3] = bp3;  lmask[tok][16 + c * 4 + 3] = bn3;
            }
        }
    }
    __syncthreads();

    // ---- phase 2: gather this lane's token masks into VGPRs and PIN them ----
    u32 m[64];
    {
        const u64* mrow = &lmask[lane][0];
        #pragma unroll
        for (int k = 0; k < 32; ++k) {
            const u64 v = mrow[k];
            m[2 * k]     = (u32)v;
            m[2 * k + 1] = (u32)(v >> 32);
        }
    }
    #pragma unroll
    for (int i = 0; i < 64; ++i) {
        asm volatile("" : "+v"(m[i]));   // opaque def: forbids LDS remat
    }

    // ---- phase 3: 64 tiles for this wave, SGPR-streamed signatures ----
    const int tbase = __builtin_amdgcn_readfirstlane(w * 64);  // provably uniform
    int bestkey = 0x7fffffff;
    float* drow = dist_out + (size_t)(tok0 + lane) * NT + tbase;

    #pragma unroll
    for (int half = 0; half < 2; ++half) {
        float dbuf[32];
        #pragma unroll
        for (int u = 0; u < 32; ++u) {
            const int t = tbase + half * 32 + u;
            const u32* __restrict__ srow = (const u32*)(sig + (size_t)t * 32);
            int a0 = 0, a1 = 0, a2 = 0, a3 = 0;
            #pragma unroll
            for (int k = 0; k < 64; k += 4) {
                a0 += __popc(m[k + 0] ^ srow[k + 0]);
                a1 += __popc(m[k + 1] ^ srow[k + 1]);
                a2 += __popc(m[k + 2] ^ srow[k + 2]);
                a3 += __popc(m[k + 3] ^ srow[k + 3]);
            }
            const int dist = (a0 + a1) + (a2 + a3);
            bestkey = min(bestkey, (dist << 8) | t);
            dbuf[u] = (float)dist;
        }
        // burst-store 32 floats = one aligned 128B line per lane
        float* dst = drow + half * 32;
        #pragma unroll
        for (int q = 0; q < 8; ++q) {
            float4 dv;
            dv.x = dbuf[4 * q + 0]; dv.y = dbuf[4 * q + 1];
            dv.z = dbuf[4 * q + 2]; dv.w = dbuf[4 * q + 3];
            *(float4*)(dst + 4 * q) = dv;
        }
    }

    // ---- combine the 4 tile-quarters for argmin ----
    lkey[w][lane] = bestkey;
    __syncthreads();
    if (w == 0) {
        const int k = min(min(lkey[0][lane], lkey[1][lane]),
                          min(lkey[2][lane], lkey[3][lane]));
        idx_out[tok0 + lane] = (float)(k & 255);
    }
}

extern "C" void kernel_launch(void* const* d_in, const int* in_sizes, int n_in,
                              void* d_out, int out_size, void* d_ws, size_t ws_size,
                              hipStream_t stream)
{
    const float* x      = (const float*)d_in[0];
    const float* base   = (const float*)d_in[1];
    const float* deltas = (const float*)d_in[2];

    u64* sig = (u64*)d_ws;                           // 256*32*8 = 64 KB

    float* idx_out  = (float*)d_out;                 // N floats (tile indices)
    float* dist_out = idx_out + NTOK;                // N*T floats

    sig_kernel<<<NT, 64, 0, stream>>>(base, deltas, sig);
    dist_kernel<<<NTOK / 64, 256, 0, stream>>>(x, sig, idx_out, dist_out);
}

// Round 8
// 240.342 us; speedup vs baseline: 1.4471x; 1.2266x over previous
//
#include <hip/hip_runtime.h>

typedef unsigned long long u64;
typedef unsigned int u32;

#define NTOK 131072
#define DIMS 1024
#define NT   256

// ---------------------------------------------------------------------------
// Kernel A: build ternary signatures as 2-plane bitmasks, TRANSPOSED layout:
//   sigT[kc*2048 + t*8 + j]  (u32), kc = word-chunk 0..7, t = tile, j = 0..7.
// u32 word index w32 = 2*W (+1 for hi half), W = u64 word: pos plane
// W = c*4+j in 0..15, neg plane W = 16 + c*4+j. Chunk kc = w32>>3.
// Per chunk a wave's 32 tiles are 1 KB contiguous -> scalar-cache friendly.
// ---------------------------------------------------------------------------
__global__ void sig_kernel(const float* __restrict__ base,
                           const float* __restrict__ deltas,
                           u32* __restrict__ sigT)
{
    const int t    = blockIdx.x;    // tile 0..255
    const int lane = threadIdx.x;   // 0..63
    #pragma unroll
    for (int c = 0; c < 4; ++c) {
        #pragma unroll
        for (int j = 0; j < 4; ++j) {
            const int d = c * 256 + lane * 4 + j;
            const float b  = base[d];
            const float dl = (t > 0) ? deltas[(size_t)(t - 1) * DIMS + d] : 0.0f;
            const bool use_d = (dl != 0.0f);
            const bool pos = use_d ? (dl > 0.0f) : (b > 0.0f);
            const bool neg = use_d ? (dl < 0.0f) : (b < 0.0f);
            const u64 bp = __ballot(pos);
            const u64 bn = __ballot(neg);
            if (lane == 0) {
                const int wp = 2 * (c * 4 + j);           // pos-plane u32 index
                sigT[(wp >> 3) * 2048 + t * 8 + (wp & 7)]     = (u32)bp;
                sigT[(wp >> 3) * 2048 + t * 8 + (wp & 7) + 1] = (u32)(bp >> 32);
                const int wn = 2 * (16 + c * 4 + j);      // neg-plane u32 index
                sigT[(wn >> 3) * 2048 + t * 8 + (wn & 7)]     = (u32)bn;
                sigT[(wn >> 3) * 2048 + t * 8 + (wn & 7) + 1] = (u32)(bn >> 32);
            }
        }
    }
}

// ---------------------------------------------------------------------------
// Kernel B (fused), 512 threads = 8 waves, 64 tokens/block, wave w owns
// tiles [32w, 32w+32).
// Phase 1: 8 waves x 8 tokens ballot-pack x signs into LDS lmask
//   (u32[64][68], 272B row stride: 16B-aligned, bank-spread).
// Phase 2/3 inverted nest (R7 lesson: 64 pinned mask VGPRs get spilled;
//   keep live state ~50 VGPR structurally): outer over 8 chunks of 8 u32
//   mask words -- lane reads its token's 32B chunk from LDS (2x
//   ds_read_b128, 16 per wave TOTAL), inner unrolled over 32 tiles
//   accumulating acc[t] += popc(chunk ^ sigT-chunk) (xor + v_bcnt-acc).
// Epilogue: per-lane argmin over acc, burst-store 32 floats (one aligned
//   128B line per lane), cross-wave argmin via 2KB LDS.
// ---------------------------------------------------------------------------
__global__ __launch_bounds__(512, 4)
void dist_kernel(const float* __restrict__ x,
                 const u32* __restrict__ sigT,
                 float* __restrict__ idx_out,
                 float* __restrict__ dist_out)
{
    __shared__ u32 lmask[64][68];   // 17408 B
    __shared__ int lkey[8][64];     // 2 KB

    const int lane = threadIdx.x & 63;
    const int w    = threadIdx.x >> 6;
    const int tok0 = blockIdx.x * 64;

    // ---- phase 1: ballot-pack 64 token rows into LDS (wave w: 8 tokens) ----
    for (int tk = 0; tk < 8; ++tk) {
        const int tok = w * 8 + tk;
        const float4* xr = (const float4*)(x + (size_t)(tok0 + tok) * DIMS);
        #pragma unroll
        for (int c = 0; c < 4; ++c) {
            const float4 v = xr[c * 64 + lane];
            const u64 bp0 = __ballot(v.x > 0.0f); const u64 bn0 = __ballot(v.x < 0.0f);
            const u64 bp1 = __ballot(v.y > 0.0f); const u64 bn1 = __ballot(v.y < 0.0f);
            const u64 bp2 = __ballot(v.z > 0.0f); const u64 bn2 = __ballot(v.z < 0.0f);
            const u64 bp3 = __ballot(v.w > 0.0f); const u64 bn3 = __ballot(v.w < 0.0f);
            if (lane == 0) {
                u64* row = (u64*)&lmask[tok][0];          // 272B stride: 8B-aligned
                row[c * 4 + 0] = bp0;  row[16 + c * 4 + 0] = bn0;
                row[c * 4 + 1] = bp1;  row[16 + c * 4 + 1] = bn1;
                row[c * 4 + 2] = bp2;  row[16 + c * 4 + 2] = bn2;
                row[c * 4 + 3] = bp3;  row[16 + c * 4 + 3] = bn3;
            }
        }
    }
    __syncthreads();

    // ---- phase 2: chunk-major xor/popcount accumulation ----
    const int wbase = __builtin_amdgcn_readfirstlane(w) * 32;  // provably uniform
    u32 acc[32];
    #pragma unroll
    for (int t = 0; t < 32; ++t) acc[t] = 0;

    for (int kc = 0; kc < 8; ++kc) {
        const uint4 ma = *(const uint4*)&lmask[lane][kc * 8];
        const uint4 mb = *(const uint4*)&lmask[lane][kc * 8 + 4];
        const u32* __restrict__ sp = sigT + kc * 2048 + wbase * 8;  // 1KB contiguous
        #pragma unroll
        for (int t = 0; t < 32; ++t) {
            const u32* __restrict__ s8 = sp + t * 8;
            acc[t] += __popc(ma.x ^ s8[0]) + __popc(ma.y ^ s8[1])
                    + __popc(ma.z ^ s8[2]) + __popc(ma.w ^ s8[3])
                    + __popc(mb.x ^ s8[4]) + __popc(mb.y ^ s8[5])
                    + __popc(mb.z ^ s8[6]) + __popc(mb.w ^ s8[7]);
        }
    }

    // ---- epilogue: argmin + burst store (one 128B line per lane) ----
    int bestkey = 0x7fffffff;
    #pragma unroll
    for (int t = 0; t < 32; ++t)
        bestkey = min(bestkey, ((int)acc[t] << 8) | (wbase + t));

    float* drow = dist_out + (size_t)(tok0 + lane) * NT + wbase;
    #pragma unroll
    for (int q = 0; q < 8; ++q) {
        float4 dv;
        dv.x = (float)acc[4 * q + 0]; dv.y = (float)acc[4 * q + 1];
        dv.z = (float)acc[4 * q + 2]; dv.w = (float)acc[4 * q + 3];
        *(float4*)(drow + 4 * q) = dv;
    }

    lkey[w][lane] = bestkey;
    __syncthreads();
    if (w == 0) {
        int k = lkey[0][lane];
        #pragma unroll
        for (int i = 1; i < 8; ++i) k = min(k, lkey[i][lane]);
        idx_out[tok0 + lane] = (float)(k & 255);
    }
}

extern "C" void kernel_launch(void* const* d_in, const int* in_sizes, int n_in,
                              void* d_out, int out_size, void* d_ws, size_t ws_size,
                              hipStream_t stream)
{
    const float* x      = (const float*)d_in[0];
    const float* base   = (const float*)d_in[1];
    const float* deltas = (const float*)d_in[2];

    u32* sigT = (u32*)d_ws;                          // 8*256*8*4 = 64 KB

    float* idx_out  = (float*)d_out;                 // N floats (tile indices)
    float* dist_out = idx_out + NTOK;                // N*T floats

    sig_kernel<<<NT, 64, 0, stream>>>(base, deltas, sigT);
    dist_kernel<<<NTOK / 64, 512, 0, stream>>>(x, sigT, idx_out, dist_out);
}